// Round 19
// baseline (702.955 us; speedup 1.0000x reference)
//
#include <hip/hip_runtime.h>
#include <hip/hip_bf16.h>
#include <math.h>

// Timer-style transformer: B=4, C=21, N=32 tokens (P=96), S=C*N=672, D=1024,
// H=16 (hd=64), NL=2, DFF=4096. All inputs fp32; output fp32 logits [4,2].
// R19 = R16/R18 base (536us plateau) + BN=256 wide tiles on QKV/FFN1 only
// (staged bytes/output -25% under the fixed per-CU drain-rate model;
// 72KB LDS -> 2 blk/CU, acc 128 VGPR). FFN2/O-proj/head stay 128^2 as the
// within-run control. Bounded-downside A/B.

typedef unsigned short u16;
typedef __attribute__((ext_vector_type(8))) __bf16 bf16x8;
typedef __attribute__((ext_vector_type(4))) float f32x4;

#define DEVI __device__ __forceinline__

DEVI u16 f2b(float f){
  union { float f; unsigned u; } x; x.f = f;
  unsigned r = x.u + 0x7fffu + ((x.u >> 16) & 1u);   // RNE
  return (u16)(r >> 16);
}

DEVI void gload16(const void* g, void* l){
  __builtin_amdgcn_global_load_lds(
      (const __attribute__((address_space(1))) unsigned int*)g,
      (__attribute__((address_space(3))) unsigned int*)l,
      16, 0, 0);
}

DEVI float block_sum(float v){
  __shared__ float lds[4];
  #pragma unroll
  for (int o = 32; o > 0; o >>= 1) v += __shfl_xor(v, o);
  if ((threadIdx.x & 63) == 0) lds[threadIdx.x >> 6] = v;
  __syncthreads();
  v = lds[0] + lds[1] + lds[2] + lds[3];
  __syncthreads();
  return v;
}

// ---------------------------------------------------------------------------
// gemm2: BMxBN tile (4 waves 2x2, wave tile BM/2 x BN/2), BK=32, 3-slot
// rotation LDS pipeline:
//   prologue: stage(s0,t0); stage(s1,t1)
//   iter t:   lgkmcnt(0) ; vmcnt(VM|0) ; s_barrier   <- one sync point
//             ds_read slot t%3 ; MFMA ; stage((t+2)%3)
// COALESCED k-fastest staging: slot s -> row=s>>2, kgS=s&3; global source
// col8 = kgS ^ f(row), f(row)=(row>>1)&3 (same-64B-line permutation keeps
// coalescing; fragment reads land 2 lanes/bank-group = conflict-free).
// Fragment read granule = row*4 + (kg ^ f(row)).
// Bijective XCD swizzle + N-stripes; split-K via z. K % 32 == 0 required.
// EPI: 0=f32, 1=f32+bf16, 2=bf16, 3=gelu->bf16.
// ---------------------------------------------------------------------------
template<int BM, int BN, int EPI>
__global__ __launch_bounds__(256) void gemm2(
    const u16* __restrict__ A0, long sA1, long sA2, int lda,
    const u16* __restrict__ B0, long sB1, long sB2, int ldb,
    float* __restrict__ Cf0, long sCf1, long sCf2, int ldc,
    u16* __restrict__ Cb0, long sCb1, long sCb2, int ldcb,
    const float* __restrict__ bias,
    int M, int N, int K, int Kchunk, int zdiv, int sw)
{
  constexpr int WM = BM/2, WN = BN/2, FM = WM/16, FN = WN/16;
  constexpr int RA = (BM*4)/256, RB = (BN*4)/256;
  constexpr int VM = RA + RB;     // loads per stage per thread

  const int nbn = gridDim.x, nbm = gridDim.y;
  const int per = nbm * nbn;
  const int nwg = per * gridDim.z;
  int gid = ((int)blockIdx.z * nbm + (int)blockIdx.y) * nbn + (int)blockIdx.x;
  int q = nwg >> 3, r = nwg & 7, xcd = gid & 7, pos = gid >> 3;
  int cid = (xcd < r ? xcd*(q+1) : r*(q+1) + (xcd-r)*q) + pos;
  int z = cid / per, rem = cid % per;
  int bm, bn;
  {
    int stripe = rem / (sw*nbm), loc = rem % (sw*nbm);
    bm = loc / sw; bn = stripe*sw + loc % sw;
  }

  const int zq = z / zdiv, zr = z % zdiv;
  const long k0 = (long)zr * Kchunk;
  const u16* A = A0 + zq*sA1 + zr*sA2 + k0;
  const u16* B = B0 + zq*sB1 + zr*sB2 + k0;

  const int tid = threadIdx.x;
  const int lane = tid & 63, wave = tid >> 6;
  const int l16 = lane & 15, lk = lane >> 4;
  const int wr = wave >> 1, wc = wave & 1;
  const int m0 = bm * BM, n0 = bn * BN;

  __shared__ u16 sA[3][4*BM*8];
  __shared__ u16 sB[3][4*BN*8];

  const u16* abase[RA];
  #pragma unroll
  for (int it = 0; it < RA; ++it){
    int s = it*256 + tid;
    int row = s >> 2, kgS = s & 3;
    int col8 = kgS ^ ((row >> 1) & 3);
    int gr = m0 + row; if (gr > M-1) gr = M-1;
    abase[it] = A + (long)gr*lda + col8*8;
  }
  const u16* bbase[RB];
  #pragma unroll
  for (int it = 0; it < RB; ++it){
    int s = it*256 + tid;
    int row = s >> 2, kgS = s & 3;
    int col8 = kgS ^ ((row >> 1) & 3);
    int gc = n0 + row; if (gc > N-1) gc = N-1;
    bbase[it] = B + (long)gc*ldb + col8*8;
  }

  auto stage = [&](int buf, int kt){
    #pragma unroll
    for (int it = 0; it < RA; ++it)
      gload16(abase[it] + kt, &sA[buf][(it*256 + tid)*8]);
    #pragma unroll
    for (int it = 0; it < RB; ++it)
      gload16(bbase[it] + kt, &sB[buf][(it*256 + tid)*8]);
  };

  f32x4 acc[FM][FN];
  const f32x4 z4 = {0.f, 0.f, 0.f, 0.f};
  #pragma unroll
  for (int i = 0; i < FM; ++i)
    #pragma unroll
    for (int j = 0; j < FN; ++j) acc[i][j] = z4;

  const int nk = K >> 5;
  stage(0, 0);
  if (nk > 1) stage(1, 32);
  for (int t = 0; t < nk; ++t){
    asm volatile("s_waitcnt lgkmcnt(0)" ::: "memory");
    if (t + 1 < nk) asm volatile("s_waitcnt vmcnt(%0)" :: "i"(VM) : "memory");
    else            asm volatile("s_waitcnt vmcnt(0)" ::: "memory");
    __builtin_amdgcn_sched_barrier(0);
    __builtin_amdgcn_s_barrier();
    __builtin_amdgcn_sched_barrier(0);

    const int slot = t % 3;
    bf16x8 af[FM], bf[FN];
    #pragma unroll
    for (int fm = 0; fm < FM; ++fm){
      int row = wr*WM + fm*16 + l16;
      af[fm] = *(const bf16x8*)&sA[slot][(row*4 + (lk ^ ((row >> 1) & 3)))*8];
    }
    #pragma unroll
    for (int fn = 0; fn < FN; ++fn){
      int col = wc*WN + fn*16 + l16;
      bf[fn] = *(const bf16x8*)&sB[slot][(col*4 + (lk ^ ((col >> 1) & 3)))*8];
    }
    #pragma unroll
    for (int fm = 0; fm < FM; ++fm)
      #pragma unroll
      for (int fn = 0; fn < FN; ++fn)
        acc[fm][fn] = __builtin_amdgcn_mfma_f32_16x16x32_bf16(af[fm], bf[fn], acc[fm][fn], 0, 0, 0);

    if (t + 2 < nk) stage((t + 2) % 3, (t + 2) << 5);
    __builtin_amdgcn_sched_barrier(0);
  }

  // C/D layout: col = lane&15, row = (lane>>4)*4 + reg
  float* Cf = (EPI==0 || EPI==1) ? Cf0 + zq*sCf1 + zr*sCf2 : nullptr;
  u16*  Cb = (EPI!=0) ? Cb0 + zq*sCb1 + zr*sCb2 : nullptr;
  #pragma unroll
  for (int fm = 0; fm < FM; ++fm){
    #pragma unroll
    for (int fn = 0; fn < FN; ++fn){
      int col = n0 + wc*WN + fn*16 + l16;
      if (col < N){
        float bv = bias ? bias[col] : 0.f;
        #pragma unroll
        for (int i = 0; i < 4; ++i){
          int row = m0 + wr*WM + fm*16 + lk*4 + i;
          if (row < M){
            float v = acc[fm][fn][i] + bv;
            if (EPI == 3) v = 0.5f * v * (1.f + erff(v * 0.70710678118f));
            if (EPI == 0 || EPI == 1) Cf[(long)row*ldc + col] = v;
            if (EPI != 0) Cb[(long)row*ldcb + col] = f2b(v);
          }
        }
      }
    }
  }
}

// ---------------------------------------------------------------------------
// Fused flash attention (R11: setprio around MFMA clusters).
// ---------------------------------------------------------------------------
__global__ __launch_bounds__(256) void flash_attn(
    const u16* __restrict__ qkv, const u16* __restrict__ vt,
    u16* __restrict__ att)
{
  const int qt = blockIdx.x, bh = blockIdx.y;
  const int b = bh >> 4, h = bh & 15;
  const int tid = threadIdx.x, lane = tid & 63, w = tid >> 6;
  const int l16 = lane & 15, lk = lane >> 4;

  __shared__ u16 P_lds[4][16][72];

  const int qrow = qt*64 + w*16 + l16;
  const int qc = qrow < 672 ? qrow : 671;
  const int qn = qc & 31;

  const u16* qbase = qkv + ((long)b*672 + qc)*3072 + h*64;
  bf16x8 qf[2];
  qf[0] = *(const bf16x8*)(qbase + lk*8);
  qf[1] = *(const bf16x8*)(qbase + 32 + lk*8);

  const u16* kbase = qkv + (long)b*672*3072 + 1024 + h*64;
  const u16* vbase = vt + (long)bh*64*672;

  f32x4 oacc[4];
  const f32x4 z4 = {0.f,0.f,0.f,0.f};
  #pragma unroll
  for (int j = 0; j < 4; ++j) oacc[j] = z4;
  float m_run = -1e30f, lsum = 0.f;

  for (int t = 0; t < 11; ++t){
    const int kv0 = t*64;
    bf16x8 kf[4][2];
    #pragma unroll
    for (int j = 0; j < 4; ++j){
      int krow = kv0 + j*16 + l16; if (krow > 671) krow = 671;
      const u16* kp = kbase + (long)krow*3072 + lk*8;
      kf[j][0] = *(const bf16x8*)(kp);
      kf[j][1] = *(const bf16x8*)(kp + 32);
    }
    bf16x8 vf[4][2];
    #pragma unroll
    for (int j = 0; j < 4; ++j){
      const u16* vp = vbase + (long)(j*16 + l16)*672 + kv0 + lk*8;
      vf[j][0] = *(const bf16x8*)(vp);
      vf[j][1] = *(const bf16x8*)(vp + 32);
    }

    f32x4 sacc[4];
    __builtin_amdgcn_s_setprio(1);
    #pragma unroll
    for (int j = 0; j < 4; ++j){
      sacc[j] = z4;
      sacc[j] = __builtin_amdgcn_mfma_f32_16x16x32_bf16(kf[j][0], qf[0], sacc[j], 0, 0, 0);
      sacc[j] = __builtin_amdgcn_mfma_f32_16x16x32_bf16(kf[j][1], qf[1], sacc[j], 0, 0, 0);
    }
    __builtin_amdgcn_s_setprio(0);

    float vals[16];
    float mx = -1e30f;
    #pragma unroll
    for (int j = 0; j < 4; ++j)
      #pragma unroll
      for (int i = 0; i < 4; ++i){
        int kv = kv0 + j*16 + lk*4 + i;
        bool ok = ((kv & 31) <= qn) && (kv < 672);
        float v = ok ? sacc[j][i] * 0.125f : -1e30f;
        vals[j*4+i] = v;
        mx = fmaxf(mx, v);
      }
    mx = fmaxf(mx, __shfl_xor(mx, 16));
    mx = fmaxf(mx, __shfl_xor(mx, 32));
    float m_new = fmaxf(m_run, mx);
    float alpha = __expf(m_run - m_new);
    float ps = 0.f;
    #pragma unroll
    for (int i = 0; i < 16; ++i){
      float e = (vals[i] > -1e29f) ? __expf(vals[i] - m_new) : 0.f;
      vals[i] = e; ps += e;
    }
    ps += __shfl_xor(ps, 16);
    ps += __shfl_xor(ps, 32);
    lsum = lsum * alpha + ps;
    m_run = m_new;
    #pragma unroll
    for (int j = 0; j < 4; ++j)
      #pragma unroll
      for (int i = 0; i < 4; ++i) oacc[j][i] *= alpha;

    #pragma unroll
    for (int j = 0; j < 4; ++j){
      unsigned lo = (unsigned)f2b(vals[j*4+0]) | ((unsigned)f2b(vals[j*4+1]) << 16);
      unsigned hi = (unsigned)f2b(vals[j*4+2]) | ((unsigned)f2b(vals[j*4+3]) << 16);
      unsigned long long pk = (unsigned long long)lo | ((unsigned long long)hi << 32);
      *(unsigned long long*)&P_lds[w][l16][j*16 + lk*4] = pk;
    }

    bf16x8 pf0 = *(const bf16x8*)&P_lds[w][l16][lk*8];
    bf16x8 pf1 = *(const bf16x8*)&P_lds[w][l16][32 + lk*8];
    __builtin_amdgcn_s_setprio(1);
    #pragma unroll
    for (int j = 0; j < 4; ++j){
      oacc[j] = __builtin_amdgcn_mfma_f32_16x16x32_bf16(vf[j][0], pf0, oacc[j], 0, 0, 0);
      oacc[j] = __builtin_amdgcn_mfma_f32_16x16x32_bf16(vf[j][1], pf1, oacc[j], 0, 0, 0);
    }
    __builtin_amdgcn_s_setprio(0);
  }

  if (qrow < 672){
    float inv = 1.f / lsum;
    u16* orow = att + ((long)b*672 + qrow)*1024 + h*64;
    #pragma unroll
    for (int j = 0; j < 4; ++j){
      unsigned lo = (unsigned)f2b(oacc[j][0]*inv) | ((unsigned)f2b(oacc[j][1]*inv) << 16);
      unsigned hi = (unsigned)f2b(oacc[j][2]*inv) | ((unsigned)f2b(oacc[j][3]*inv) << 16);
      unsigned long long pk = (unsigned long long)lo | ((unsigned long long)hi << 32);
      *(unsigned long long*)(orow + j*16 + lk*4) = pk;
    }
  }
}

// --------------------------- small kernels ---------------------------------

__global__ __launch_bounds__(256) void instnorm_stats(
    const float* __restrict__ x, float* __restrict__ mean, float* __restrict__ rstd)
{
  int bc = blockIdx.x;
  int b = bc / 21, c = bc % 21;
  const float* p = x + (long)b*3072*21 + c;
  float s = 0.f, sq = 0.f;
  for (int l = threadIdx.x; l < 3072; l += 256){
    float u = p[(long)l*21];
    s += u; sq += u*u;
  }
  s = block_sum(s); sq = block_sum(sq);
  if (threadIdx.x == 0){
    float m = s * (1.f/3072.f);
    float var = sq * (1.f/3072.f) - m*m;
    float sd = fmaxf(sqrtf(var + 1e-6f), 1e-5f);
    mean[bc] = m; rstd[bc] = 1.f / sd;
  }
}

__global__ __launch_bounds__(256) void build_windows(
    const float* __restrict__ x, const float* __restrict__ mean,
    const float* __restrict__ rstd, u16* __restrict__ xw)
{
  int idx = blockIdx.x*256 + threadIdx.x;
  if (idx >= 2688*96) return;
  int r = idx / 96, p = idx % 96;
  int b = r / 672, rem = r % 672, c = rem / 32, n = rem % 32;
  int l = n*96 + p;
  int bc = b*21 + c;
  float u = (x[((long)b*3072 + l)*21 + c] - mean[bc]) * rstd[bc];
  xw[idx] = f2b(u);
}

__global__ __launch_bounds__(256) void transpose_cast(
    const float* __restrict__ in, long sIn, u16* __restrict__ out, long sOut,
    int R, int C)
{
  in += (long)blockIdx.z * sIn; out += (long)blockIdx.z * sOut;
  __shared__ float tile[32][33];
  int ct = blockIdx.x, rt = blockIdx.y;
  int tx = threadIdx.x & 31, ty = threadIdx.x >> 5;
  #pragma unroll
  for (int i = 0; i < 4; ++i){
    int r = rt*32 + ty + i*8, c = ct*32 + tx;
    tile[ty+i*8][tx] = (r < R && c < C) ? in[(long)r*C + c] : 0.f;
  }
  __syncthreads();
  #pragma unroll
  for (int i = 0; i < 4; ++i){
    int oc = rt*32 + tx;
    int orow = ct*32 + ty + i*8;
    if (orow < C && oc < R) out[(long)orow*R + oc] = f2b(tile[tx][ty+i*8]);
  }
}

__global__ __launch_bounds__(256) void transpose_sq(
    const float* __restrict__ Wq, const float* __restrict__ Wk,
    const float* __restrict__ Wv, const float* __restrict__ Wo,
    u16* __restrict__ wqkvT, u16* __restrict__ woT)
{
  int zz = blockIdx.z, l = zz >> 2, t = zz & 3;
  const float* src = (t==0) ? Wq : (t==1) ? Wk : (t==2) ? Wv : Wo;
  src += (size_t)l*1024*1024;
  u16* dst = (t < 3) ? wqkvT + (size_t)l*3072*1024 + (size_t)t*1024*1024
                     : woT + (size_t)l*1024*1024;
  __shared__ float tile[32][33];
  int ct = blockIdx.x, rt = blockIdx.y;
  int tx = threadIdx.x & 31, ty = threadIdx.x >> 5;
  #pragma unroll
  for (int i = 0; i < 4; ++i)
    tile[ty+i*8][tx] = src[(long)(rt*32 + ty + i*8)*1024 + ct*32 + tx];
  __syncthreads();
  #pragma unroll
  for (int i = 0; i < 4; ++i)
    dst[(long)(ct*32 + ty + i*8)*1024 + rt*32 + tx] = f2b(tile[tx][ty+i*8]);
}

__global__ __launch_bounds__(256) void transpose_vt(
    const u16* __restrict__ qkv, u16* __restrict__ vt)
{
  int zz = blockIdx.z; int b = zz >> 4, hh = zz & 15;
  const u16* in = qkv + (long)b*672*3072 + 2048 + hh*64;
  u16* out = vt + (long)zz*64*672;
  __shared__ u16 tile[32][33];
  int ct = blockIdx.x, rt = blockIdx.y;
  int tx = threadIdx.x & 31, ty = threadIdx.x >> 5;
  #pragma unroll
  for (int i = 0; i < 4; ++i){
    int s = rt*32 + ty + i*8, e = ct*32 + tx;
    tile[ty+i*8][tx] = in[(long)s*3072 + e];
  }
  __syncthreads();
  #pragma unroll
  for (int i = 0; i < 4; ++i){
    int e = ct*32 + ty + i*8, s = rt*32 + tx;
    out[(long)e*672 + s] = tile[tx][ty+i*8];
  }
}

__global__ __launch_bounds__(256) void concat_qkv_bias(
    const float* __restrict__ bq, const float* __restrict__ bk,
    const float* __restrict__ bv, float* __restrict__ bqkv)
{
  int i = blockIdx.x*256 + threadIdx.x;
  if (i >= 2*3072) return;
  int l = i / 3072, j = i % 3072;
  float v = (j < 1024) ? bq[l*1024 + j]
          : (j < 2048) ? bk[l*1024 + j - 1024]
                       : bv[l*1024 + j - 2048];
  bqkv[i] = v;
}

// h_out = LN(X + sum_slices(R) + cbias) * g + be ; D=1024, float4-vectorized.
__global__ __launch_bounds__(256) void ln_kernel(
    const float* __restrict__ X, const float* __restrict__ R, int nsl, long ssl,
    const float* __restrict__ cb,
    const float* __restrict__ g, const float* __restrict__ be,
    float* __restrict__ outF, u16* __restrict__ outB)
{
  long row = blockIdx.x;
  long base = row * 1024;
  int d4 = threadIdx.x * 4;
  float4 v = *(const float4*)&X[base + d4];
  for (int sl = 0; sl < nsl; ++sl){
    float4 rv = *(const float4*)&R[(long)sl*ssl + base + d4];
    v.x += rv.x; v.y += rv.y; v.z += rv.z; v.w += rv.w;
  }
  if (cb){
    float4 cv = *(const float4*)&cb[d4];
    v.x += cv.x; v.y += cv.y; v.z += cv.z; v.w += cv.w;
  }
  float s = v.x + v.y + v.z + v.w;
  float sq = v.x*v.x + v.y*v.y + v.z*v.z + v.w*v.w;
  s = block_sum(s); sq = block_sum(sq);
  float mean = s * (1.f/1024.f);
  float var = sq * (1.f/1024.f) - mean*mean;
  float rst = rsqrtf(var + 1e-5f);
  float4 gv = *(const float4*)&g[d4];
  float4 bv = *(const float4*)&be[d4];
  float o0 = (v.x - mean) * rst * gv.x + bv.x;
  float o1 = (v.y - mean) * rst * gv.y + bv.y;
  float o2 = (v.z - mean) * rst * gv.z + bv.z;
  float o3 = (v.w - mean) * rst * gv.w + bv.w;
  if (outF){
    float4 ov = {o0, o1, o2, o3};
    *(float4*)&outF[base + d4] = ov;
  }
  if (outB){
    unsigned lo = (unsigned)f2b(o0) | ((unsigned)f2b(o1) << 16);
    unsigned hi = (unsigned)f2b(o2) | ((unsigned)f2b(o3) << 16);
    unsigned long long pk = (unsigned long long)lo | ((unsigned long long)hi << 32);
    *(unsigned long long*)&outB[base + d4] = pk;
  }
}

// feat[b][o] = headB[o] + mean over 672 rows x 8 K-slices of dec, nan_to_num
__global__ __launch_bounds__(256) void pool_kernel(
    const float* __restrict__ dec, const float* __restrict__ headB,
    float* __restrict__ feat)
{
  int b = blockIdx.x, o = blockIdx.y;
  float s = 0.f;
  for (int i = threadIdx.x; i < 672*8; i += 256){
    int sl = i / 672, r = i % 672;
    s += dec[(long)sl*2688*96 + ((long)b*672 + r)*96 + o];
  }
  s = block_sum(s);
  if (threadIdx.x == 0){
    float f = headB[o] + s * (1.f/672.f);
    if (!isfinite(f)) f = 0.f;
    feat[b*96 + o] = f;
  }
}

__global__ __launch_bounds__(256) void classifier(
    const float* __restrict__ feat,
    const float* __restrict__ w1, const float* __restrict__ b1,
    const float* __restrict__ w2, const float* __restrict__ b2,
    const float* __restrict__ w3, const float* __restrict__ b3,
    float* __restrict__ out)
{
  __shared__ float f[384];
  __shared__ float z1[1024];
  __shared__ float z2[256];
  int t = threadIdx.x;
  for (int i = t; i < 384; i += 256) f[i] = feat[i];
  __syncthreads();
  for (int o = t; o < 1024; o += 256){
    int b = o >> 8, j = o & 255;
    float s = b1[j];
    for (int p = 0; p < 96; ++p) s += f[b*96 + p] * w1[p*256 + j];
    z1[o] = fmaxf(s, 0.f);
  }
  __syncthreads();
  for (int o = t; o < 256; o += 256){
    int b = o >> 6, j = o & 63;
    float s = b2[j];
    for (int p = 0; p < 256; ++p) s += z1[b*256 + p] * w2[p*64 + j];
    z2[o] = fmaxf(s, 0.f);
  }
  __syncthreads();
  if (t < 8){
    int b = t >> 1, j = t & 1;
    float s = b3[j];
    for (int p = 0; p < 64; ++p) s += z2[b*64 + p] * w3[p*2 + j];
    out[t] = s;
  }
}

// ---------------------------------------------------------------------------

static inline int pick_sw(int nbn){
  if (nbn % 8 == 0) return 8;
  if (nbn % 4 == 0) return 4;
  if (nbn % 2 == 0) return 2;
  return 1;
}

extern "C" void kernel_launch(void* const* d_in, const int* in_sizes, int n_in,
                              void* d_out, int out_size, void* d_ws, size_t ws_size,
                              hipStream_t stream)
{
  (void)in_sizes; (void)n_in; (void)out_size; (void)ws_size;
  const float* x     = (const float*)d_in[0];
  const float* embW  = (const float*)d_in[3];
  const float* embB  = (const float*)d_in[4];
  const float* Wq    = (const float*)d_in[5];
  const float* bq    = (const float*)d_in[6];
  const float* Wk    = (const float*)d_in[7];
  const float* bk    = (const float*)d_in[8];
  const float* Wv    = (const float*)d_in[9];
  const float* bv    = (const float*)d_in[10];
  const float* Wo    = (const float*)d_in[11];
  const float* bo    = (const float*)d_in[12];
  const float* W1    = (const float*)d_in[13];
  const float* b1    = (const float*)d_in[14];
  const float* W2    = (const float*)d_in[15];
  const float* b2    = (const float*)d_in[16];
  const float* ln1s  = (const float*)d_in[17];
  const float* ln1b  = (const float*)d_in[18];
  const float* ln2s  = (const float*)d_in[19];
  const float* ln2b  = (const float*)d_in[20];
  const float* lnfs  = (const float*)d_in[21];
  const float* lnfb  = (const float*)d_in[22];
  const float* headW = (const float*)d_in[23];
  const float* headB = (const float*)d_in[24];
  const float* c1W   = (const float*)d_in[25];
  const float* c1B   = (const float*)d_in[26];
  const float* c2W   = (const float*)d_in[27];
  const float* c2B   = (const float*)d_in[28];
  const float* c3W   = (const float*)d_in[29];
  const float* c3B   = (const float*)d_in[30];
  float* out = (float*)d_out;

  // ---- workspace arena ----
  char* w = (char*)d_ws; size_t off = 0;
  auto alloc = [&](size_t bytes)->void*{
    void* p = w + off; off = (off + bytes + 255) & ~(size_t)255; return p; };
  u16*   embT  = (u16*)alloc((size_t)96*1024*2);
  u16*   wqkvT = (u16*)alloc((size_t)2*3072*1024*2);
  u16*   woT   = (u16*)alloc((size_t)2*1024*1024*2);
  u16*   w1T   = (u16*)alloc((size_t)2*4096*1024*2);
  u16*   w2T   = (u16*)alloc((size_t)2*1024*4096*2);
  u16*   headT = (u16*)alloc((size_t)96*1024*2);
  float* bqkv  = (float*)alloc((size_t)2*3072*4);
  float* meanp = (float*)alloc(84*4);
  float* rstdp = (float*)alloc(84*4);
  u16*   xw    = (u16*)alloc((size_t)2688*96*2);
  float* h     = (float*)alloc((size_t)2688*1024*4);
  u16*   hb    = (u16*)alloc((size_t)2688*1024*2);
  u16*   qkv   = (u16*)alloc((size_t)2688*3072*2);
  u16*   vt    = (u16*)alloc((size_t)64*64*672*2);
  u16*   att   = (u16*)alloc((size_t)2688*1024*2);
  float* feat  = (float*)alloc(384*4);
  size_t un_off = off;
  float* tmp  = (float*)(w + un_off);                       // 2 x fp32 [2688,1024]
  u16*   ffnb = (u16*)(w + un_off + (size_t)2*2688*1024*4); // bf16 [2688,4096]
  float* dec  = (float*)(w + un_off);                       // 8 x fp32 [2688,96]

  // ---- weight prep ----
  transpose_sq<<<dim3(32,32,8), 256, 0, stream>>>(Wq, Wk, Wv, Wo, wqkvT, woT);
  transpose_cast<<<dim3(32,3,1),  256, 0, stream>>>(embW, 0, embT, 0, 96, 1024);
  transpose_cast<<<dim3(3,32,1),  256, 0, stream>>>(headW, 0, headT, 0, 1024, 96);
  transpose_cast<<<dim3(128,32,2),256, 0, stream>>>(W1, (long)1024*4096, w1T, (long)4096*1024, 1024, 4096);
  transpose_cast<<<dim3(32,128,2),256, 0, stream>>>(W2, (long)4096*1024, w2T, (long)1024*4096, 4096, 1024);
  concat_qkv_bias<<<(2*3072+255)/256, 256, 0, stream>>>(bq, bk, bv, bqkv);

  // ---- front-end ----
  instnorm_stats<<<84, 256, 0, stream>>>(x, meanp, rstdp);
  build_windows<<<(2688*96+255)/256, 256, 0, stream>>>(x, meanp, rstdp, xw);

  // embed: [2688,96] @ [96,1024] -> h fp32 + hb bf16
  gemm2<128,128,1><<<dim3(8,21,1),256,0,stream>>>(
      xw,0,0,96, embT,0,0,96, h,0,0,1024, hb,0,0,1024, embB,
      2688,1024,96,0,1, pick_sw(8));

  for (int l = 0; l < 2; ++l){
    // fused QKV [2688,3072] -- BN=256 wide tile (grid 12x21=252)
    gemm2<128,256,2><<<dim3(12,21,1),256,0,stream>>>(
        hb,0,0,1024, wqkvT+(size_t)l*3072*1024,0,0,1024,
        nullptr,0,0,0, qkv,0,0,3072, bqkv+l*3072,
        2688,3072,1024,0,1, pick_sw(12));
    transpose_vt<<<dim3(2,21,64),256,0,stream>>>(qkv, vt);

    // fused attention -> att (bf16)
    flash_attn<<<dim3(11,64),256,0,stream>>>(qkv, vt, att);

    // O-projection, split-K x2 (control: 128^2)
    gemm2<128,128,0><<<dim3(8,21,2),256,0,stream>>>(
        att,0,0,1024, woT+(size_t)l*1024*1024,0,0,1024,
        tmp,0,(long)2688*1024,1024, nullptr,0,0,0, nullptr,
        2688,1024,512,512,2, pick_sw(8));
    ln_kernel<<<2688,256,0,stream>>>(h, tmp, 2, (long)2688*1024, bo+l*1024,
                                     ln1s+l*1024, ln1b+l*1024, h, hb);
    // FFN1 [2688,4096] gelu -- BN=256 wide tile (grid 16x21=336)
    gemm2<128,256,3><<<dim3(16,21,1),256,0,stream>>>(
        hb,0,0,1024, w1T+(size_t)l*4096*1024,0,0,1024,
        nullptr,0,0,0, ffnb,0,0,4096, b1+l*4096,
        2688,4096,1024,0,1, pick_sw(16));
    // FFN2 split-K x2 (control: 128^2)
    gemm2<128,128,0><<<dim3(8,21,2),256,0,stream>>>(
        ffnb,0,0,4096, w2T+(size_t)l*4096*1024,0,0,4096,
        tmp,0,(long)2688*1024,1024, nullptr,0,0,0, nullptr,
        2688,1024,2048,2048,2, pick_sw(8));
    ln_kernel<<<2688,256,0,stream>>>(h, tmp, 2, (long)2688*1024, b2+l*1024,
                                     ln2s+l*1024, ln2b+l*1024, h, hb);
  }

  // final norm + head (split-K x8, bias in pool) + pooling + classifier
  ln_kernel<<<2688,256,0,stream>>>(h, nullptr, 0, 0, nullptr, lnfs, lnfb, nullptr, hb);
  gemm2<128,128,0><<<dim3(1,21,8),256,0,stream>>>(
      hb,0,0,1024, headT,0,0,1024,
      dec,0,(long)2688*96,96, nullptr,0,0,0, nullptr,
      2688,96,128,128,8, pick_sw(1));
  pool_kernel<<<dim3(4,96),256,0,stream>>>(dec, headB, feat);
  classifier<<<1,256,0,stream>>>(feat, c1W,c1B, c2W,c2B, c3W,c3B, out);
}

// Round 20
// 534.863 us; speedup vs baseline: 1.3143x; 1.3143x over previous
//
#include <hip/hip_runtime.h>
#include <hip/hip_bf16.h>
#include <math.h>

// Timer-style transformer: B=4, C=21, N=32 tokens (P=96), S=C*N=672, D=1024,
// H=16 (hd=64), NL=2, DFF=4096. All inputs fp32; output fp32 logits [4,2].
// FINAL = R16 exact (best measured: 536.0us; R18 re-measure 540.0 = noise).
// Coalesced k-fastest staging with same-64B-line XOR swizzle, 3-slot LDS
// rotation with counted vmcnt, XCD-bijective grid swizzle, fused flash
// attention, split-K x2 + slice-summing vectorized LN.
// R17 (depth-2) null; R19 (BN=256) regressed -> plateau confirmed.

typedef unsigned short u16;
typedef __attribute__((ext_vector_type(8))) __bf16 bf16x8;
typedef __attribute__((ext_vector_type(4))) float f32x4;

#define DEVI __device__ __forceinline__

DEVI u16 f2b(float f){
  union { float f; unsigned u; } x; x.f = f;
  unsigned r = x.u + 0x7fffu + ((x.u >> 16) & 1u);   // RNE
  return (u16)(r >> 16);
}

DEVI void gload16(const void* g, void* l){
  __builtin_amdgcn_global_load_lds(
      (const __attribute__((address_space(1))) unsigned int*)g,
      (__attribute__((address_space(3))) unsigned int*)l,
      16, 0, 0);
}

DEVI float block_sum(float v){
  __shared__ float lds[4];
  #pragma unroll
  for (int o = 32; o > 0; o >>= 1) v += __shfl_xor(v, o);
  if ((threadIdx.x & 63) == 0) lds[threadIdx.x >> 6] = v;
  __syncthreads();
  v = lds[0] + lds[1] + lds[2] + lds[3];
  __syncthreads();
  return v;
}

// ---------------------------------------------------------------------------
// gemm2: 128x128 tile, 4 waves (2x2), BK=32, 3-slot rotation LDS pipeline:
//   prologue: stage(s0,t0); stage(s1,t1)
//   iter t:   lgkmcnt(0) ; vmcnt(8|0) ; s_barrier   <- one sync point
//             ds_read slot t%3 ; MFMA ; stage((t+2)%3)
// COALESCED k-fastest staging: slot s -> row=s>>2, kgS=s&3; global source
// col8 = kgS ^ f(row), f(row)=(row>>1)&3 (same-64B-line permutation keeps
// coalescing; fragment reads land 2 lanes/bank-group = conflict-free).
// Fragment read granule = row*4 + (kg ^ f(row)).
// Bijective XCD swizzle + N-stripes; split-K via z. K % 32 == 0 required.
// EPI: 0=f32, 1=f32+bf16, 2=bf16, 3=gelu->bf16.
// ---------------------------------------------------------------------------
template<int BM, int BN, int EPI>
__global__ __launch_bounds__(256) void gemm2(
    const u16* __restrict__ A0, long sA1, long sA2, int lda,
    const u16* __restrict__ B0, long sB1, long sB2, int ldb,
    float* __restrict__ Cf0, long sCf1, long sCf2, int ldc,
    u16* __restrict__ Cb0, long sCb1, long sCb2, int ldcb,
    const float* __restrict__ bias,
    int M, int N, int K, int Kchunk, int zdiv, int sw)
{
  constexpr int WM = BM/2, WN = BN/2, FM = WM/16, FN = WN/16;
  constexpr int RA = (BM*4)/256, RB = (BN*4)/256;
  constexpr int VM = RA + RB;     // loads per stage per thread (=8 for 128^2)

  const int nbn = gridDim.x, nbm = gridDim.y;
  const int per = nbm * nbn;
  const int nwg = per * gridDim.z;
  int gid = ((int)blockIdx.z * nbm + (int)blockIdx.y) * nbn + (int)blockIdx.x;
  int q = nwg >> 3, r = nwg & 7, xcd = gid & 7, pos = gid >> 3;
  int cid = (xcd < r ? xcd*(q+1) : r*(q+1) + (xcd-r)*q) + pos;
  int z = cid / per, rem = cid % per;
  int bm, bn;
  {
    int stripe = rem / (sw*nbm), loc = rem % (sw*nbm);
    bm = loc / sw; bn = stripe*sw + loc % sw;
  }

  const int zq = z / zdiv, zr = z % zdiv;
  const long k0 = (long)zr * Kchunk;
  const u16* A = A0 + zq*sA1 + zr*sA2 + k0;
  const u16* B = B0 + zq*sB1 + zr*sB2 + k0;

  const int tid = threadIdx.x;
  const int lane = tid & 63, wave = tid >> 6;
  const int l16 = lane & 15, lk = lane >> 4;
  const int wr = wave >> 1, wc = wave & 1;
  const int m0 = bm * BM, n0 = bn * BN;

  __shared__ u16 sA[3][4*BM*8];
  __shared__ u16 sB[3][4*BN*8];

  const u16* abase[RA];
  #pragma unroll
  for (int it = 0; it < RA; ++it){
    int s = it*256 + tid;
    int row = s >> 2, kgS = s & 3;
    int col8 = kgS ^ ((row >> 1) & 3);
    int gr = m0 + row; if (gr > M-1) gr = M-1;
    abase[it] = A + (long)gr*lda + col8*8;
  }
  const u16* bbase[RB];
  #pragma unroll
  for (int it = 0; it < RB; ++it){
    int s = it*256 + tid;
    int row = s >> 2, kgS = s & 3;
    int col8 = kgS ^ ((row >> 1) & 3);
    int gc = n0 + row; if (gc > N-1) gc = N-1;
    bbase[it] = B + (long)gc*ldb + col8*8;
  }

  auto stage = [&](int buf, int kt){
    #pragma unroll
    for (int it = 0; it < RA; ++it)
      gload16(abase[it] + kt, &sA[buf][(it*256 + tid)*8]);
    #pragma unroll
    for (int it = 0; it < RB; ++it)
      gload16(bbase[it] + kt, &sB[buf][(it*256 + tid)*8]);
  };

  f32x4 acc[FM][FN];
  const f32x4 z4 = {0.f, 0.f, 0.f, 0.f};
  #pragma unroll
  for (int i = 0; i < FM; ++i)
    #pragma unroll
    for (int j = 0; j < FN; ++j) acc[i][j] = z4;

  const int nk = K >> 5;
  stage(0, 0);
  if (nk > 1) stage(1, 32);
  for (int t = 0; t < nk; ++t){
    asm volatile("s_waitcnt lgkmcnt(0)" ::: "memory");
    if (t + 1 < nk) asm volatile("s_waitcnt vmcnt(%0)" :: "i"(VM) : "memory");
    else            asm volatile("s_waitcnt vmcnt(0)" ::: "memory");
    __builtin_amdgcn_sched_barrier(0);
    __builtin_amdgcn_s_barrier();
    __builtin_amdgcn_sched_barrier(0);

    const int slot = t % 3;
    bf16x8 af[FM], bf[FN];
    #pragma unroll
    for (int fm = 0; fm < FM; ++fm){
      int row = wr*WM + fm*16 + l16;
      af[fm] = *(const bf16x8*)&sA[slot][(row*4 + (lk ^ ((row >> 1) & 3)))*8];
    }
    #pragma unroll
    for (int fn = 0; fn < FN; ++fn){
      int col = wc*WN + fn*16 + l16;
      bf[fn] = *(const bf16x8*)&sB[slot][(col*4 + (lk ^ ((col >> 1) & 3)))*8];
    }
    #pragma unroll
    for (int fm = 0; fm < FM; ++fm)
      #pragma unroll
      for (int fn = 0; fn < FN; ++fn)
        acc[fm][fn] = __builtin_amdgcn_mfma_f32_16x16x32_bf16(af[fm], bf[fn], acc[fm][fn], 0, 0, 0);

    if (t + 2 < nk) stage((t + 2) % 3, (t + 2) << 5);
    __builtin_amdgcn_sched_barrier(0);
  }

  // C/D layout: col = lane&15, row = (lane>>4)*4 + reg
  float* Cf = (EPI==0 || EPI==1) ? Cf0 + zq*sCf1 + zr*sCf2 : nullptr;
  u16*  Cb = (EPI!=0) ? Cb0 + zq*sCb1 + zr*sCb2 : nullptr;
  #pragma unroll
  for (int fm = 0; fm < FM; ++fm){
    #pragma unroll
    for (int fn = 0; fn < FN; ++fn){
      int col = n0 + wc*WN + fn*16 + l16;
      if (col < N){
        float bv = bias ? bias[col] : 0.f;
        #pragma unroll
        for (int i = 0; i < 4; ++i){
          int row = m0 + wr*WM + fm*16 + lk*4 + i;
          if (row < M){
            float v = acc[fm][fn][i] + bv;
            if (EPI == 3) v = 0.5f * v * (1.f + erff(v * 0.70710678118f));
            if (EPI == 0 || EPI == 1) Cf[(long)row*ldc + col] = v;
            if (EPI != 0) Cb[(long)row*ldcb + col] = f2b(v);
          }
        }
      }
    }
  }
}

// ---------------------------------------------------------------------------
// Fused flash attention (R11: setprio around MFMA clusters).
// ---------------------------------------------------------------------------
__global__ __launch_bounds__(256) void flash_attn(
    const u16* __restrict__ qkv, const u16* __restrict__ vt,
    u16* __restrict__ att)
{
  const int qt = blockIdx.x, bh = blockIdx.y;
  const int b = bh >> 4, h = bh & 15;
  const int tid = threadIdx.x, lane = tid & 63, w = tid >> 6;
  const int l16 = lane & 15, lk = lane >> 4;

  __shared__ u16 P_lds[4][16][72];

  const int qrow = qt*64 + w*16 + l16;
  const int qc = qrow < 672 ? qrow : 671;
  const int qn = qc & 31;

  const u16* qbase = qkv + ((long)b*672 + qc)*3072 + h*64;
  bf16x8 qf[2];
  qf[0] = *(const bf16x8*)(qbase + lk*8);
  qf[1] = *(const bf16x8*)(qbase + 32 + lk*8);

  const u16* kbase = qkv + (long)b*672*3072 + 1024 + h*64;
  const u16* vbase = vt + (long)bh*64*672;

  f32x4 oacc[4];
  const f32x4 z4 = {0.f,0.f,0.f,0.f};
  #pragma unroll
  for (int j = 0; j < 4; ++j) oacc[j] = z4;
  float m_run = -1e30f, lsum = 0.f;

  for (int t = 0; t < 11; ++t){
    const int kv0 = t*64;
    bf16x8 kf[4][2];
    #pragma unroll
    for (int j = 0; j < 4; ++j){
      int krow = kv0 + j*16 + l16; if (krow > 671) krow = 671;
      const u16* kp = kbase + (long)krow*3072 + lk*8;
      kf[j][0] = *(const bf16x8*)(kp);
      kf[j][1] = *(const bf16x8*)(kp + 32);
    }
    bf16x8 vf[4][2];
    #pragma unroll
    for (int j = 0; j < 4; ++j){
      const u16* vp = vbase + (long)(j*16 + l16)*672 + kv0 + lk*8;
      vf[j][0] = *(const bf16x8*)(vp);
      vf[j][1] = *(const bf16x8*)(vp + 32);
    }

    f32x4 sacc[4];
    __builtin_amdgcn_s_setprio(1);
    #pragma unroll
    for (int j = 0; j < 4; ++j){
      sacc[j] = z4;
      sacc[j] = __builtin_amdgcn_mfma_f32_16x16x32_bf16(kf[j][0], qf[0], sacc[j], 0, 0, 0);
      sacc[j] = __builtin_amdgcn_mfma_f32_16x16x32_bf16(kf[j][1], qf[1], sacc[j], 0, 0, 0);
    }
    __builtin_amdgcn_s_setprio(0);

    float vals[16];
    float mx = -1e30f;
    #pragma unroll
    for (int j = 0; j < 4; ++j)
      #pragma unroll
      for (int i = 0; i < 4; ++i){
        int kv = kv0 + j*16 + lk*4 + i;
        bool ok = ((kv & 31) <= qn) && (kv < 672);
        float v = ok ? sacc[j][i] * 0.125f : -1e30f;
        vals[j*4+i] = v;
        mx = fmaxf(mx, v);
      }
    mx = fmaxf(mx, __shfl_xor(mx, 16));
    mx = fmaxf(mx, __shfl_xor(mx, 32));
    float m_new = fmaxf(m_run, mx);
    float alpha = __expf(m_run - m_new);
    float ps = 0.f;
    #pragma unroll
    for (int i = 0; i < 16; ++i){
      float e = (vals[i] > -1e29f) ? __expf(vals[i] - m_new) : 0.f;
      vals[i] = e; ps += e;
    }
    ps += __shfl_xor(ps, 16);
    ps += __shfl_xor(ps, 32);
    lsum = lsum * alpha + ps;
    m_run = m_new;
    #pragma unroll
    for (int j = 0; j < 4; ++j)
      #pragma unroll
      for (int i = 0; i < 4; ++i) oacc[j][i] *= alpha;

    #pragma unroll
    for (int j = 0; j < 4; ++j){
      unsigned lo = (unsigned)f2b(vals[j*4+0]) | ((unsigned)f2b(vals[j*4+1]) << 16);
      unsigned hi = (unsigned)f2b(vals[j*4+2]) | ((unsigned)f2b(vals[j*4+3]) << 16);
      unsigned long long pk = (unsigned long long)lo | ((unsigned long long)hi << 32);
      *(unsigned long long*)&P_lds[w][l16][j*16 + lk*4] = pk;
    }

    bf16x8 pf0 = *(const bf16x8*)&P_lds[w][l16][lk*8];
    bf16x8 pf1 = *(const bf16x8*)&P_lds[w][l16][32 + lk*8];
    __builtin_amdgcn_s_setprio(1);
    #pragma unroll
    for (int j = 0; j < 4; ++j){
      oacc[j] = __builtin_amdgcn_mfma_f32_16x16x32_bf16(vf[j][0], pf0, oacc[j], 0, 0, 0);
      oacc[j] = __builtin_amdgcn_mfma_f32_16x16x32_bf16(vf[j][1], pf1, oacc[j], 0, 0, 0);
    }
    __builtin_amdgcn_s_setprio(0);
  }

  if (qrow < 672){
    float inv = 1.f / lsum;
    u16* orow = att + ((long)b*672 + qrow)*1024 + h*64;
    #pragma unroll
    for (int j = 0; j < 4; ++j){
      unsigned lo = (unsigned)f2b(oacc[j][0]*inv) | ((unsigned)f2b(oacc[j][1]*inv) << 16);
      unsigned hi = (unsigned)f2b(oacc[j][2]*inv) | ((unsigned)f2b(oacc[j][3]*inv) << 16);
      unsigned long long pk = (unsigned long long)lo | ((unsigned long long)hi << 32);
      *(unsigned long long*)(orow + j*16 + lk*4) = pk;
    }
  }
}

// --------------------------- small kernels ---------------------------------

__global__ __launch_bounds__(256) void instnorm_stats(
    const float* __restrict__ x, float* __restrict__ mean, float* __restrict__ rstd)
{
  int bc = blockIdx.x;
  int b = bc / 21, c = bc % 21;
  const float* p = x + (long)b*3072*21 + c;
  float s = 0.f, sq = 0.f;
  for (int l = threadIdx.x; l < 3072; l += 256){
    float u = p[(long)l*21];
    s += u; sq += u*u;
  }
  s = block_sum(s); sq = block_sum(sq);
  if (threadIdx.x == 0){
    float m = s * (1.f/3072.f);
    float var = sq * (1.f/3072.f) - m*m;
    float sd = fmaxf(sqrtf(var + 1e-6f), 1e-5f);
    mean[bc] = m; rstd[bc] = 1.f / sd;
  }
}

__global__ __launch_bounds__(256) void build_windows(
    const float* __restrict__ x, const float* __restrict__ mean,
    const float* __restrict__ rstd, u16* __restrict__ xw)
{
  int idx = blockIdx.x*256 + threadIdx.x;
  if (idx >= 2688*96) return;
  int r = idx / 96, p = idx % 96;
  int b = r / 672, rem = r % 672, c = rem / 32, n = rem % 32;
  int l = n*96 + p;
  int bc = b*21 + c;
  float u = (x[((long)b*3072 + l)*21 + c] - mean[bc]) * rstd[bc];
  xw[idx] = f2b(u);
}

__global__ __launch_bounds__(256) void transpose_cast(
    const float* __restrict__ in, long sIn, u16* __restrict__ out, long sOut,
    int R, int C)
{
  in += (long)blockIdx.z * sIn; out += (long)blockIdx.z * sOut;
  __shared__ float tile[32][33];
  int ct = blockIdx.x, rt = blockIdx.y;
  int tx = threadIdx.x & 31, ty = threadIdx.x >> 5;
  #pragma unroll
  for (int i = 0; i < 4; ++i){
    int r = rt*32 + ty + i*8, c = ct*32 + tx;
    tile[ty+i*8][tx] = (r < R && c < C) ? in[(long)r*C + c] : 0.f;
  }
  __syncthreads();
  #pragma unroll
  for (int i = 0; i < 4; ++i){
    int oc = rt*32 + tx;
    int orow = ct*32 + ty + i*8;
    if (orow < C && oc < R) out[(long)orow*R + oc] = f2b(tile[tx][ty+i*8]);
  }
}

__global__ __launch_bounds__(256) void transpose_sq(
    const float* __restrict__ Wq, const float* __restrict__ Wk,
    const float* __restrict__ Wv, const float* __restrict__ Wo,
    u16* __restrict__ wqkvT, u16* __restrict__ woT)
{
  int zz = blockIdx.z, l = zz >> 2, t = zz & 3;
  const float* src = (t==0) ? Wq : (t==1) ? Wk : (t==2) ? Wv : Wo;
  src += (size_t)l*1024*1024;
  u16* dst = (t < 3) ? wqkvT + (size_t)l*3072*1024 + (size_t)t*1024*1024
                     : woT + (size_t)l*1024*1024;
  __shared__ float tile[32][33];
  int ct = blockIdx.x, rt = blockIdx.y;
  int tx = threadIdx.x & 31, ty = threadIdx.x >> 5;
  #pragma unroll
  for (int i = 0; i < 4; ++i)
    tile[ty+i*8][tx] = src[(long)(rt*32 + ty + i*8)*1024 + ct*32 + tx];
  __syncthreads();
  #pragma unroll
  for (int i = 0; i < 4; ++i)
    dst[(long)(ct*32 + ty + i*8)*1024 + rt*32 + tx] = f2b(tile[tx][ty+i*8]);
}

__global__ __launch_bounds__(256) void transpose_vt(
    const u16* __restrict__ qkv, u16* __restrict__ vt)
{
  int zz = blockIdx.z; int b = zz >> 4, hh = zz & 15;
  const u16* in = qkv + (long)b*672*3072 + 2048 + hh*64;
  u16* out = vt + (long)zz*64*672;
  __shared__ u16 tile[32][33];
  int ct = blockIdx.x, rt = blockIdx.y;
  int tx = threadIdx.x & 31, ty = threadIdx.x >> 5;
  #pragma unroll
  for (int i = 0; i < 4; ++i){
    int s = rt*32 + ty + i*8, e = ct*32 + tx;
    tile[ty+i*8][tx] = in[(long)s*3072 + e];
  }
  __syncthreads();
  #pragma unroll
  for (int i = 0; i < 4; ++i){
    int e = ct*32 + ty + i*8, s = rt*32 + tx;
    out[(long)e*672 + s] = tile[tx][ty+i*8];
  }
}

__global__ __launch_bounds__(256) void concat_qkv_bias(
    const float* __restrict__ bq, const float* __restrict__ bk,
    const float* __restrict__ bv, float* __restrict__ bqkv)
{
  int i = blockIdx.x*256 + threadIdx.x;
  if (i >= 2*3072) return;
  int l = i / 3072, j = i % 3072;
  float v = (j < 1024) ? bq[l*1024 + j]
          : (j < 2048) ? bk[l*1024 + j - 1024]
                       : bv[l*1024 + j - 2048];
  bqkv[i] = v;
}

// h_out = LN(X + sum_slices(R) + cbias) * g + be ; D=1024, float4-vectorized.
__global__ __launch_bounds__(256) void ln_kernel(
    const float* __restrict__ X, const float* __restrict__ R, int nsl, long ssl,
    const float* __restrict__ cb,
    const float* __restrict__ g, const float* __restrict__ be,
    float* __restrict__ outF, u16* __restrict__ outB)
{
  long row = blockIdx.x;
  long base = row * 1024;
  int d4 = threadIdx.x * 4;
  float4 v = *(const float4*)&X[base + d4];
  for (int sl = 0; sl < nsl; ++sl){
    float4 rv = *(const float4*)&R[(long)sl*ssl + base + d4];
    v.x += rv.x; v.y += rv.y; v.z += rv.z; v.w += rv.w;
  }
  if (cb){
    float4 cv = *(const float4*)&cb[d4];
    v.x += cv.x; v.y += cv.y; v.z += cv.z; v.w += cv.w;
  }
  float s = v.x + v.y + v.z + v.w;
  float sq = v.x*v.x + v.y*v.y + v.z*v.z + v.w*v.w;
  s = block_sum(s); sq = block_sum(sq);
  float mean = s * (1.f/1024.f);
  float var = sq * (1.f/1024.f) - mean*mean;
  float rst = rsqrtf(var + 1e-5f);
  float4 gv = *(const float4*)&g[d4];
  float4 bv = *(const float4*)&be[d4];
  float o0 = (v.x - mean) * rst * gv.x + bv.x;
  float o1 = (v.y - mean) * rst * gv.y + bv.y;
  float o2 = (v.z - mean) * rst * gv.z + bv.z;
  float o3 = (v.w - mean) * rst * gv.w + bv.w;
  if (outF){
    float4 ov = {o0, o1, o2, o3};
    *(float4*)&outF[base + d4] = ov;
  }
  if (outB){
    unsigned lo = (unsigned)f2b(o0) | ((unsigned)f2b(o1) << 16);
    unsigned hi = (unsigned)f2b(o2) | ((unsigned)f2b(o3) << 16);
    unsigned long long pk = (unsigned long long)lo | ((unsigned long long)hi << 32);
    *(unsigned long long*)&outB[base + d4] = pk;
  }
}

// feat[b][o] = headB[o] + mean over 672 rows x 8 K-slices of dec, nan_to_num
__global__ __launch_bounds__(256) void pool_kernel(
    const float* __restrict__ dec, const float* __restrict__ headB,
    float* __restrict__ feat)
{
  int b = blockIdx.x, o = blockIdx.y;
  float s = 0.f;
  for (int i = threadIdx.x; i < 672*8; i += 256){
    int sl = i / 672, r = i % 672;
    s += dec[(long)sl*2688*96 + ((long)b*672 + r)*96 + o];
  }
  s = block_sum(s);
  if (threadIdx.x == 0){
    float f = headB[o] + s * (1.f/672.f);
    if (!isfinite(f)) f = 0.f;
    feat[b*96 + o] = f;
  }
}

__global__ __launch_bounds__(256) void classifier(
    const float* __restrict__ feat,
    const float* __restrict__ w1, const float* __restrict__ b1,
    const float* __restrict__ w2, const float* __restrict__ b2,
    const float* __restrict__ w3, const float* __restrict__ b3,
    float* __restrict__ out)
{
  __shared__ float f[384];
  __shared__ float z1[1024];
  __shared__ float z2[256];
  int t = threadIdx.x;
  for (int i = t; i < 384; i += 256) f[i] = feat[i];
  __syncthreads();
  for (int o = t; o < 1024; o += 256){
    int b = o >> 8, j = o & 255;
    float s = b1[j];
    for (int p = 0; p < 96; ++p) s += f[b*96 + p] * w1[p*256 + j];
    z1[o] = fmaxf(s, 0.f);
  }
  __syncthreads();
  for (int o = t; o < 256; o += 256){
    int b = o >> 6, j = o & 63;
    float s = b2[j];
    for (int p = 0; p < 256; ++p) s += z1[b*256 + p] * w2[p*64 + j];
    z2[o] = fmaxf(s, 0.f);
  }
  __syncthreads();
  if (t < 8){
    int b = t >> 1, j = t & 1;
    float s = b3[j];
    for (int p = 0; p < 64; ++p) s += z2[b*64 + p] * w3[p*2 + j];
    out[t] = s;
  }
}

// ---------------------------------------------------------------------------

static inline int pick_sw(int nbn){
  if (nbn % 8 == 0) return 8;
  if (nbn % 4 == 0) return 4;
  if (nbn % 2 == 0) return 2;
  return 1;
}

extern "C" void kernel_launch(void* const* d_in, const int* in_sizes, int n_in,
                              void* d_out, int out_size, void* d_ws, size_t ws_size,
                              hipStream_t stream)
{
  (void)in_sizes; (void)n_in; (void)out_size; (void)ws_size;
  const float* x     = (const float*)d_in[0];
  const float* embW  = (const float*)d_in[3];
  const float* embB  = (const float*)d_in[4];
  const float* Wq    = (const float*)d_in[5];
  const float* bq    = (const float*)d_in[6];
  const float* Wk    = (const float*)d_in[7];
  const float* bk    = (const float*)d_in[8];
  const float* Wv    = (const float*)d_in[9];
  const float* bv    = (const float*)d_in[10];
  const float* Wo    = (const float*)d_in[11];
  const float* bo    = (const float*)d_in[12];
  const float* W1    = (const float*)d_in[13];
  const float* b1    = (const float*)d_in[14];
  const float* W2    = (const float*)d_in[15];
  const float* b2    = (const float*)d_in[16];
  const float* ln1s  = (const float*)d_in[17];
  const float* ln1b  = (const float*)d_in[18];
  const float* ln2s  = (const float*)d_in[19];
  const float* ln2b  = (const float*)d_in[20];
  const float* lnfs  = (const float*)d_in[21];
  const float* lnfb  = (const float*)d_in[22];
  const float* headW = (const float*)d_in[23];
  const float* headB = (const float*)d_in[24];
  const float* c1W   = (const float*)d_in[25];
  const float* c1B   = (const float*)d_in[26];
  const float* c2W   = (const float*)d_in[27];
  const float* c2B   = (const float*)d_in[28];
  const float* c3W   = (const float*)d_in[29];
  const float* c3B   = (const float*)d_in[30];
  float* out = (float*)d_out;

  // ---- workspace arena ----
  char* w = (char*)d_ws; size_t off = 0;
  auto alloc = [&](size_t bytes)->void*{
    void* p = w + off; off = (off + bytes + 255) & ~(size_t)255; return p; };
  u16*   embT  = (u16*)alloc((size_t)96*1024*2);
  u16*   wqkvT = (u16*)alloc((size_t)2*3072*1024*2);
  u16*   woT   = (u16*)alloc((size_t)2*1024*1024*2);
  u16*   w1T   = (u16*)alloc((size_t)2*4096*1024*2);
  u16*   w2T   = (u16*)alloc((size_t)2*1024*4096*2);
  u16*   headT = (u16*)alloc((size_t)96*1024*2);
  float* bqkv  = (float*)alloc((size_t)2*3072*4);
  float* meanp = (float*)alloc(84*4);
  float* rstdp = (float*)alloc(84*4);
  u16*   xw    = (u16*)alloc((size_t)2688*96*2);
  float* h     = (float*)alloc((size_t)2688*1024*4);
  u16*   hb    = (u16*)alloc((size_t)2688*1024*2);
  u16*   qkv   = (u16*)alloc((size_t)2688*3072*2);
  u16*   vt    = (u16*)alloc((size_t)64*64*672*2);
  u16*   att   = (u16*)alloc((size_t)2688*1024*2);
  float* feat  = (float*)alloc(384*4);
  size_t un_off = off;
  float* tmp  = (float*)(w + un_off);                       // 2 x fp32 [2688,1024]
  u16*   ffnb = (u16*)(w + un_off + (size_t)2*2688*1024*4); // bf16 [2688,4096]
  float* dec  = (float*)(w + un_off);                       // 8 x fp32 [2688,96]

  // ---- weight prep ----
  transpose_sq<<<dim3(32,32,8), 256, 0, stream>>>(Wq, Wk, Wv, Wo, wqkvT, woT);
  transpose_cast<<<dim3(32,3,1),  256, 0, stream>>>(embW, 0, embT, 0, 96, 1024);
  transpose_cast<<<dim3(3,32,1),  256, 0, stream>>>(headW, 0, headT, 0, 1024, 96);
  transpose_cast<<<dim3(128,32,2),256, 0, stream>>>(W1, (long)1024*4096, w1T, (long)4096*1024, 1024, 4096);
  transpose_cast<<<dim3(32,128,2),256, 0, stream>>>(W2, (long)4096*1024, w2T, (long)1024*4096, 4096, 1024);
  concat_qkv_bias<<<(2*3072+255)/256, 256, 0, stream>>>(bq, bk, bv, bqkv);

  // ---- front-end ----
  instnorm_stats<<<84, 256, 0, stream>>>(x, meanp, rstdp);
  build_windows<<<(2688*96+255)/256, 256, 0, stream>>>(x, meanp, rstdp, xw);

  // embed: [2688,96] @ [96,1024] -> h fp32 + hb bf16
  gemm2<128,128,1><<<dim3(8,21,1),256,0,stream>>>(
      xw,0,0,96, embT,0,0,96, h,0,0,1024, hb,0,0,1024, embB,
      2688,1024,96,0,1, pick_sw(8));

  for (int l = 0; l < 2; ++l){
    // fused QKV [2688,3072]
    gemm2<128,128,2><<<dim3(24,21,1),256,0,stream>>>(
        hb,0,0,1024, wqkvT+(size_t)l*3072*1024,0,0,1024,
        nullptr,0,0,0, qkv,0,0,3072, bqkv+l*3072,
        2688,3072,1024,0,1, pick_sw(24));
    transpose_vt<<<dim3(2,21,64),256,0,stream>>>(qkv, vt);

    // fused attention -> att (bf16)
    flash_attn<<<dim3(11,64),256,0,stream>>>(qkv, vt, att);

    // O-projection, split-K x2 -> 2 tmp slices (bias added in ln1)
    gemm2<128,128,0><<<dim3(8,21,2),256,0,stream>>>(
        att,0,0,1024, woT+(size_t)l*1024*1024,0,0,1024,
        tmp,0,(long)2688*1024,1024, nullptr,0,0,0, nullptr,
        2688,1024,512,512,2, pick_sw(8));
    ln_kernel<<<2688,256,0,stream>>>(h, tmp, 2, (long)2688*1024, bo+l*1024,
                                     ln1s+l*1024, ln1b+l*1024, h, hb);
    // FFN1 [2688,4096] gelu
    gemm2<128,128,3><<<dim3(32,21,1),256,0,stream>>>(
        hb,0,0,1024, w1T+(size_t)l*4096*1024,0,0,1024,
        nullptr,0,0,0, ffnb,0,0,4096, b1+l*4096,
        2688,4096,1024,0,1, pick_sw(32));
    // FFN2 split-K x2 -> 2 tmp slices
    gemm2<128,128,0><<<dim3(8,21,2),256,0,stream>>>(
        ffnb,0,0,4096, w2T+(size_t)l*4096*1024,0,0,4096,
        tmp,0,(long)2688*1024,1024, nullptr,0,0,0, nullptr,
        2688,1024,2048,2048,2, pick_sw(8));
    ln_kernel<<<2688,256,0,stream>>>(h, tmp, 2, (long)2688*1024, b2+l*1024,
                                     ln2s+l*1024, ln2b+l*1024, h, hb);
  }

  // final norm + head (split-K x8, bias in pool) + pooling + classifier
  ln_kernel<<<2688,256,0,stream>>>(h, nullptr, 0, 0, nullptr, lnfs, lnfb, nullptr, hb);
  gemm2<128,128,0><<<dim3(1,21,8),256,0,stream>>>(
      hb,0,0,1024, headT,0,0,1024,
      dec,0,(long)2688*96,96, nullptr,0,0,0, nullptr,
      2688,96,128,128,8, pick_sw(1));
  pool_kernel<<<dim3(4,96),256,0,stream>>>(dec, headB, feat);
  classifier<<<1,256,0,stream>>>(feat, c1W,c1B, c2W,c2B, c3W,c3B, out);
}